// Round 16
// baseline (350.693 us; speedup 1.0000x reference)
//
#include <hip/hip_runtime.h>
#include <cstdint>
#include <cstddef>

// x[B=512, L=32, H=32, D=128]; per (l,h): Linear(128->128) -> GELU -> Linear(128->128)
// R16 = R9/R11 persistent-per-lh structure, but 512 threads: 8 waves split by
// ROWS (w>>2) x COLS (w&3). 4 waves/SIMD (was 2) = 2x independent streams to
// hide per-wave latency; full 128-B out lines stay within one wave (avoids
// R10's split-line WRITE amplification). Same 64KB LDS / 2 blocks/CU window.
#define LH      1024
#define Dd      128
#define BT      64            // batch rows per tile -> 32 KB f32 per buffer
#define NTILE   8             // 512 / 64
#define XSTRIDE (LH * Dd)

typedef __attribute__((ext_vector_type(8))) short bf16x8;
typedef __attribute__((ext_vector_type(4))) float f32x4;
typedef const __attribute__((address_space(1))) uint32_t gu32;
typedef __attribute__((address_space(3))) uint32_t lu32;

static __device__ __forceinline__ short f2bf(float f) {
  return __builtin_bit_cast(short, (__bf16)f);
}

// tanh-form GELU as one sigmoid; |diff| vs erf-gelu ~3e-3 << 0.185 threshold
static __device__ __forceinline__ float gelu_fast(float v) {
  float v2 = v * v;
  float u2 = v * (1.5957691216f + 0.0713548163f * v2);
  return v / (1.0f + __expf(-u2));
}

// LDS-only barrier: ds ops drained; global loads/stores stay in flight.
#define BAR_LGKM() do {                                          \
  __builtin_amdgcn_sched_barrier(0);                             \
  asm volatile("s_waitcnt lgkmcnt(0)" ::: "memory");             \
  __builtin_amdgcn_s_barrier();                                  \
  __builtin_amdgcn_sched_barrier(0);                             \
} while (0)

// End-of-iter barrier: vmcnt(16) retires everything except the newest 16
// vmem ops (= this tile's 16 output stores/wave); in-order retire (m135)
// proves the 4 DMA issues for tile t+1 landed. Stores drain under next GEMM1.
#define BAR_END() do {                                           \
  __builtin_amdgcn_sched_barrier(0);                             \
  asm volatile("s_waitcnt vmcnt(16) lgkmcnt(0)" ::: "memory");   \
  __builtin_amdgcn_s_barrier();                                  \
  __builtin_amdgcn_sched_barrier(0);                             \
} while (0)

__global__ __launch_bounds__(512, 4) void fused_mlp_persist(
    const float* __restrict__ x, const float* __restrict__ W1,
    const float* __restrict__ b1, const float* __restrict__ W2,
    const float* __restrict__ b2, float* __restrict__ out) {
  // 2 ping-pong buffers of 32 KB. Each: x f32 [64 rows][32 chunks of 16B],
  // chunk-index XOR-swizzled on the GLOBAL source addr (global_load_lds
  // writes LDS linearly, m104/m173). H bf16 [64][128] (16 KB) overlays bytes
  // 0..16K of the CURRENT buffer after GEMM1's reads are barrier-complete.
  __shared__ alignas(16) char smem[2][BT * Dd * 4];   // 64 KB -> 2 blocks/CU

  const int tid  = threadIdx.x;
  const int lane = tid & 63;
  const int wid  = tid >> 6;     // 8 waves
  const int lr   = lane & 15;
  const int lg   = lane >> 4;

  const int wr = wid >> 2;       // row half: rows wr*32 .. wr*32+31
  const int wc = wid & 3;        // col quarter: cols wc*32 .. wc*32+31
  const int rb = wr * 32;
  const int n0 = wc * 32;

  const int lh = blockIdx.x;     // W reuse is intra-block
  const float* w1  = W1 + (size_t)lh * (Dd * Dd);
  const float* w2  = W2 + (size_t)lh * (Dd * Dd);
  const float* xlh = x   + (size_t)lh * Dd;
  float*       olh = out + (size_t)lh * Dd;

  // stage tile t into buffer buf: 4 DMA issues/wave (8 waves x 4 = 32 slots)
  auto stage = [&](int t, int buf) {
#pragma unroll
    for (int i = 0; i < 4; ++i) {
      const int slot = wid * 4 + i;          // wave-uniform 1KB LDS slot
      const int row  = slot * 2 + (lane >> 5);
      const int cp   = lane & 31;            // chunk position in LDS
      const int c    = cp ^ (row & 15);      // global chunk (bijective swz)
      const float* g = xlh + (size_t)(t * BT + row) * XSTRIDE + c * 4;
      __builtin_amdgcn_global_load_lds((gu32*)g,
                                       (lu32*)(smem[buf] + slot * 1024),
                                       16, 0, 0);
    }
  };

  // ---- prologue: DMA tile 0; gather this wave's W fragments (cols n0..n0+31)
  // to regs under the DMA flight; biases. (Row-halves duplicate the gather;
  // the second copy is L2-hot.)
  stage(0, 0);

  bf16x8 bw1[4][2], bw2[4][2];
#pragma unroll
  for (int ks = 0; ks < 4; ++ks)
#pragma unroll
    for (int nt = 0; nt < 2; ++nt) {
      const float* p1 = w1 + (size_t)(ks * 32 + lg * 8) * Dd + n0 + nt * 16 + lr;
      const float* p2 = w2 + (size_t)(ks * 32 + lg * 8) * Dd + n0 + nt * 16 + lr;
      bf16x8 a, b;
#pragma unroll
      for (int j = 0; j < 8; ++j) { a[j] = f2bf(p1[j * Dd]); b[j] = f2bf(p2[j * Dd]); }
      bw1[ks][nt] = a;
      bw2[ks][nt] = b;
    }

  const float bb1_0 = b1[lh * Dd + n0 + lr];
  const float bb1_1 = b1[lh * Dd + n0 + 16 + lr];
  const float bb2_0 = b2[lh * Dd + n0 + lr];
  const float bb2_1 = b2[lh * Dd + n0 + 16 + lr];

  // prologue barrier: full drain (DMA(0) + W loads), once per block
  __builtin_amdgcn_sched_barrier(0);
  asm volatile("s_waitcnt vmcnt(0) lgkmcnt(0)" ::: "memory");
  __builtin_amdgcn_s_barrier();
  __builtin_amdgcn_sched_barrier(0);

  for (int t = 0; t < NTILE; ++t) {
    const int cur = t & 1;

    // DMA(t+1) -> other buffer; proven free by BAR_END(t-1).
    if (t + 1 < NTILE) stage(t + 1, cur ^ 1);

    // ---------------- GEMM1: H = gelu(X @ W1 + b1) ----------------
    f32x4 acc[2][2];
#pragma unroll
    for (int mt = 0; mt < 2; ++mt) {
      acc[mt][0] = (f32x4){bb1_0, bb1_0, bb1_0, bb1_0};
      acc[mt][1] = (f32x4){bb1_1, bb1_1, bb1_1, bb1_1};
    }
#pragma unroll
    for (int ks = 0; ks < 4; ++ks) {
      bf16x8 af[2];
#pragma unroll
      for (int mt = 0; mt < 2; ++mt) {
        const int row = rb + mt * 16 + lr;
        const int c0  = ks * 8 + lg * 2;
        const int m   = row & 15;
        const float4 lo = *(const float4*)(smem[cur] + row * 512 + ((c0)     ^ m) * 16);
        const float4 hi = *(const float4*)(smem[cur] + row * 512 + ((c0 + 1) ^ m) * 16);
        bf16x8 a;
        a[0] = f2bf(lo.x); a[1] = f2bf(lo.y); a[2] = f2bf(lo.z); a[3] = f2bf(lo.w);
        a[4] = f2bf(hi.x); a[5] = f2bf(hi.y); a[6] = f2bf(hi.z); a[7] = f2bf(hi.w);
        af[mt] = a;
      }
#pragma unroll
      for (int mt = 0; mt < 2; ++mt)
#pragma unroll
        for (int nt = 0; nt < 2; ++nt)
          acc[mt][nt] = __builtin_amdgcn_mfma_f32_16x16x32_bf16(af[mt], bw1[ks][nt], acc[mt][nt], 0, 0, 0);
    }

    // GELU in regs before the barrier
    short hv[2][2][4];
#pragma unroll
    for (int mt = 0; mt < 2; ++mt)
#pragma unroll
      for (int nt = 0; nt < 2; ++nt)
#pragma unroll
        for (int r = 0; r < 4; ++r)
          hv[mt][nt][r] = f2bf(gelu_fast(acc[mt][nt][r]));

    BAR_LGKM();   // all waves done reading x[cur]; stores/DMA stay in flight

#pragma unroll
    for (int mt = 0; mt < 2; ++mt)
#pragma unroll
      for (int nt = 0; nt < 2; ++nt) {
        const int e = n0 + nt * 16 + lr;
#pragma unroll
        for (int r = 0; r < 4; ++r) {
          const int b = rb + mt * 16 + lg * 4 + r;   // C/D row = (lane>>4)*4+reg
          const int off = (b * 256 + e * 2) ^ ((b & 7) << 4);
          *(short*)(smem[cur] + off) = hv[mt][nt][r];
        }
      }

    BAR_LGKM();   // H visible; stores/DMA still in flight

    // ---------------- GEMM2: out = H @ W2 + b2 (W2 in regs) ----------
    f32x4 acc2[2][2];
#pragma unroll
    for (int mt = 0; mt < 2; ++mt) {
      acc2[mt][0] = (f32x4){bb2_0, bb2_0, bb2_0, bb2_0};
      acc2[mt][1] = (f32x4){bb2_1, bb2_1, bb2_1, bb2_1};
    }
#pragma unroll
    for (int ks = 0; ks < 4; ++ks) {
      const int k2 = (ks * 32 + lg * 8) * 2;   // byte offset of 16B H granule
#pragma unroll
      for (int mt = 0; mt < 2; ++mt) {
        const int b = rb + mt * 16 + lr;
        const int off = (b * 256 + k2) ^ ((b & 7) << 4);
        bf16x8 a = *(const bf16x8*)(smem[cur] + off);
#pragma unroll
        for (int nt = 0; nt < 2; ++nt)
          acc2[mt][nt] = __builtin_amdgcn_mfma_f32_16x16x32_bf16(a, bw2[ks][nt], acc2[mt][nt], 0, 0, 0);
      }
    }

    // epilogue: 16 f32 stores/wave (64B contiguous per 16-lane group; the two
    // nt halves of each 128B line are adjacent instructions in one wave)
    {
      float* ob = olh + (size_t)(t * BT) * XSTRIDE;
#pragma unroll
      for (int mt = 0; mt < 2; ++mt)
#pragma unroll
        for (int nt = 0; nt < 2; ++nt) {
          const int e = n0 + nt * 16 + lr;
#pragma unroll
          for (int r = 0; r < 4; ++r) {
            const int b = rb + mt * 16 + lg * 4 + r;
            ob[(size_t)b * XSTRIDE + e] = acc2[mt][nt][r];
          }
        }
    }

    // end-of-iter: prove DMA(t+1) landed + all waves past H[cur] reads;
    // keep this tile's 16 stores in flight across the barrier.
    if (t + 1 < NTILE) BAR_END();
  }
}

extern "C" void kernel_launch(void* const* d_in, const int* in_sizes, int n_in,
                              void* d_out, int out_size, void* d_ws, size_t ws_size,
                              hipStream_t stream) {
  (void)in_sizes; (void)n_in; (void)d_ws; (void)ws_size; (void)out_size;
  const float* x  = (const float*)d_in[0];
  const float* W1 = (const float*)d_in[1];
  const float* b1 = (const float*)d_in[2];
  const float* W2 = (const float*)d_in[3];
  const float* b2 = (const float*)d_in[4];
  float* out = (float*)d_out;
  fused_mlp_persist<<<dim3(LH), dim3(512), 0, stream>>>(x, W1, b1, W2, b2, out);
}

// Round 17
// 150.116 us; speedup vs baseline: 2.3361x; 2.3361x over previous
//
#include <hip/hip_runtime.h>
#include <cstdint>
#include <cstddef>

// x[B=512, L=32, H=32, D=128]; per (l,h): Linear(128->128) -> GELU -> Linear(128->128)
// FINAL (= R9 champion, 150.3 us): persistent-per-lh; one block owns all 8
// batch-tiles of one (l,h). W gathered to regs ONCE per block (hidden under
// the tile-0 DMA flight); x DMA double-buffered across tiles via
// global_load_lds; H overlays the current x buffer.
//
// Session findings baked into this shape (R10-R16 all regressed it):
//  - x MUST be staged via global_load_lds (direct VGPR loads lose 2-3x: R12/R14)
//  - exactly {256 thr, 4 waves, BT=64, grid 1024, 2 blocks/CU} keeps the
//    L3 traffic credit (FETCH 197 MB); 512-thr or 4-blocks/CU configs blow
//    FETCH to 480-615 MB (R10/R13/R16)
//  - counted-vmcnt barriers and 3-deep DMA pipelining are perf-neutral
//    here (R11/R15) -> keep plain __syncthreads for simplicity/safety
#define LH      1024
#define Dd      128
#define BT      64            // batch rows per tile -> 32 KB f32 in LDS
#define NTILE   8             // 512 / 64
#define XSTRIDE (LH * Dd)

typedef __attribute__((ext_vector_type(8))) short bf16x8;
typedef __attribute__((ext_vector_type(4))) float f32x4;
typedef const __attribute__((address_space(1))) uint32_t gu32;
typedef __attribute__((address_space(3))) uint32_t lu32;

static __device__ __forceinline__ short f2bf(float f) {
  return __builtin_bit_cast(short, (__bf16)f);
}

// tanh-form GELU as one sigmoid; |diff| vs erf-gelu ~3e-3 << 0.185 threshold
static __device__ __forceinline__ float gelu_fast(float v) {
  float v2 = v * v;
  float u2 = v * (1.5957691216f + 0.0713548163f * v2);
  return v / (1.0f + __expf(-u2));
}

__global__ __launch_bounds__(256, 2) void fused_mlp_persist(
    const float* __restrict__ x, const float* __restrict__ W1,
    const float* __restrict__ b1, const float* __restrict__ W2,
    const float* __restrict__ b2, float* __restrict__ out) {
  // 2 ping-pong buffers. Each: x f32 [64 rows][32 chunks of 16B], chunk-index
  // XOR-swizzled on the GLOBAL source addr (global_load_lds writes LDS
  // linearly, m104/m173). H bf16 [64][128] overlays bytes 0..16K of the
  // CURRENT buffer after GEMM1's reads are barrier-complete.
  __shared__ alignas(16) char smem[2][BT * Dd * 4];   // 64 KB -> 2 blocks/CU

  const int tid  = threadIdx.x;
  const int lane = tid & 63;
  const int wid  = tid >> 6;     // 4 waves, each owns 32 N-columns
  const int lr   = lane & 15;
  const int lg   = lane >> 4;

  const int lh = blockIdx.x;     // W reuse is intra-block
  const int n0 = wid * 32;

  const float* w1  = W1 + (size_t)lh * (Dd * Dd);
  const float* w2  = W2 + (size_t)lh * (Dd * Dd);
  const float* xlh = x   + (size_t)lh * Dd;
  float*       olh = out + (size_t)lh * Dd;

  // stage tile t into buffer buf: 8 DMA issues/wave, 32 KB in flight
  auto stage = [&](int t, int buf) {
#pragma unroll
    for (int i = 0; i < 8; ++i) {
      const int slot = wid * 8 + i;          // wave-uniform 1KB LDS slot
      const int row  = slot * 2 + (lane >> 5);
      const int cp   = lane & 31;            // chunk position in LDS
      const int c    = cp ^ (row & 15);      // global chunk (bijective swz)
      const float* g = xlh + (size_t)(t * BT + row) * XSTRIDE + c * 4;
      __builtin_amdgcn_global_load_lds((gu32*)g,
                                       (lu32*)(smem[buf] + slot * 1024),
                                       16, 0, 0);
    }
  };

  // ---- prologue: DMA tile 0; gather ALL W fragments to regs (once per
  // block, hidden under the DMA flight); biases.
  stage(0, 0);

  bf16x8 bw1[4][2], bw2[4][2];
#pragma unroll
  for (int ks = 0; ks < 4; ++ks)
#pragma unroll
    for (int nt = 0; nt < 2; ++nt) {
      const float* p1 = w1 + (size_t)(ks * 32 + lg * 8) * Dd + n0 + nt * 16 + lr;
      const float* p2 = w2 + (size_t)(ks * 32 + lg * 8) * Dd + n0 + nt * 16 + lr;
      bf16x8 a, b;
#pragma unroll
      for (int j = 0; j < 8; ++j) { a[j] = f2bf(p1[j * Dd]); b[j] = f2bf(p2[j * Dd]); }
      bw1[ks][nt] = a;
      bw2[ks][nt] = b;
    }

  const float bb1_0 = b1[lh * Dd + n0 + lr];
  const float bb1_1 = b1[lh * Dd + n0 + 16 + lr];
  const float bb2_0 = b2[lh * Dd + n0 + lr];
  const float bb2_1 = b2[lh * Dd + n0 + 16 + lr];

  f32x4 accp[4];   // unused placeholder removed in R9 final; kept out

  for (int t = 0; t < NTILE; ++t) {
    const int cur = t & 1;

    // Loop-top barrier: (a) drains DMA(t) -> x[t] visible in smem[cur];
    // (b) proves every wave finished GEMM2(t-1)'s H reads from smem[cur^1],
    // so DMA(t+1) may overwrite it.
    __syncthreads();
    if (t + 1 < NTILE) stage(t + 1, cur ^ 1);

    // ---------------- GEMM1: H = gelu(X @ W1 + b1) ----------------
    f32x4 acc[4][2];
#pragma unroll
    for (int mt = 0; mt < 4; ++mt) {
      acc[mt][0] = (f32x4){bb1_0, bb1_0, bb1_0, bb1_0};
      acc[mt][1] = (f32x4){bb1_1, bb1_1, bb1_1, bb1_1};
    }
#pragma unroll
    for (int ks = 0; ks < 4; ++ks) {
      bf16x8 af[4];
#pragma unroll
      for (int mt = 0; mt < 4; ++mt) {
        const int row = mt * 16 + lr;
        const int c0  = ks * 8 + lg * 2;
        const int m   = row & 15;
        const float4 lo = *(const float4*)(smem[cur] + row * 512 + ((c0)     ^ m) * 16);
        const float4 hi = *(const float4*)(smem[cur] + row * 512 + ((c0 + 1) ^ m) * 16);
        bf16x8 a;
        a[0] = f2bf(lo.x); a[1] = f2bf(lo.y); a[2] = f2bf(lo.z); a[3] = f2bf(lo.w);
        a[4] = f2bf(hi.x); a[5] = f2bf(hi.y); a[6] = f2bf(hi.z); a[7] = f2bf(hi.w);
        af[mt] = a;
      }
#pragma unroll
      for (int mt = 0; mt < 4; ++mt)
#pragma unroll
        for (int nt = 0; nt < 2; ++nt)
          acc[mt][nt] = __builtin_amdgcn_mfma_f32_16x16x32_bf16(af[mt], bw1[ks][nt], acc[mt][nt], 0, 0, 0);
    }

    // GELU in regs, then overlay-write H into smem[cur]
    short hv[4][2][4];
#pragma unroll
    for (int mt = 0; mt < 4; ++mt)
#pragma unroll
      for (int nt = 0; nt < 2; ++nt)
#pragma unroll
        for (int r = 0; r < 4; ++r)
          hv[mt][nt][r] = f2bf(gelu_fast(acc[mt][nt][r]));

    __syncthreads();   // all waves done reading x[cur] -> safe to overlay H

#pragma unroll
    for (int mt = 0; mt < 4; ++mt)
#pragma unroll
      for (int nt = 0; nt < 2; ++nt) {
        const int e = n0 + nt * 16 + lr;
#pragma unroll
        for (int r = 0; r < 4; ++r) {
          const int b = mt * 16 + lg * 4 + r;   // C/D row = (lane>>4)*4 + reg
          const int off = (b * 256 + e * 2) ^ ((b & 7) << 4);
          *(short*)(smem[cur] + off) = hv[mt][nt][r];
        }
      }
    __syncthreads();   // H visible

    // ---------------- GEMM2: out = H @ W2 + b2 (W2 in regs) ----------
    f32x4 acc2[4][2];
#pragma unroll
    for (int mt = 0; mt < 4; ++mt) {
      acc2[mt][0] = (f32x4){bb2_0, bb2_0, bb2_0, bb2_0};
      acc2[mt][1] = (f32x4){bb2_1, bb2_1, bb2_1, bb2_1};
    }
#pragma unroll
    for (int ks = 0; ks < 4; ++ks) {
      const int k2 = (ks * 32 + lg * 8) * 2;   // byte offset of 16B H granule
#pragma unroll
      for (int mt = 0; mt < 4; ++mt) {
        const int b = mt * 16 + lr;
        const int off = (b * 256 + k2) ^ ((b & 7) << 4);
        bf16x8 a = *(const bf16x8*)(smem[cur] + off);
#pragma unroll
        for (int nt = 0; nt < 2; ++nt)
          acc2[mt][nt] = __builtin_amdgcn_mfma_f32_16x16x32_bf16(a, bw2[ks][nt], acc2[mt][nt], 0, 0, 0);
      }
    }

    // epilogue: f32 stores (64B contiguous per 16-lane group)
    {
      float* ob = olh + (size_t)(t * BT) * XSTRIDE;
#pragma unroll
      for (int mt = 0; mt < 4; ++mt)
#pragma unroll
        for (int nt = 0; nt < 2; ++nt) {
          const int e = n0 + nt * 16 + lr;
#pragma unroll
          for (int r = 0; r < 4; ++r) {
            const int b = mt * 16 + lg * 4 + r;
            ob[(size_t)b * XSTRIDE + e] = acc2[mt][nt][r];
          }
        }
    }
  }
}

extern "C" void kernel_launch(void* const* d_in, const int* in_sizes, int n_in,
                              void* d_out, int out_size, void* d_ws, size_t ws_size,
                              hipStream_t stream) {
  (void)in_sizes; (void)n_in; (void)d_ws; (void)ws_size; (void)out_size;
  const float* x  = (const float*)d_in[0];
  const float* W1 = (const float*)d_in[1];
  const float* b1 = (const float*)d_in[2];
  const float* W2 = (const float*)d_in[3];
  const float* b2 = (const float*)d_in[4];
  float* out = (float*)d_out;
  fused_mlp_persist<<<dim3(LH), dim3(256), 0, stream>>>(x, W1, b1, W2, b2, out);
}

// Round 18
// 148.398 us; speedup vs baseline: 2.3632x; 1.0116x over previous
//
#include <hip/hip_runtime.h>
#include <cstdint>
#include <cstddef>

// x[B=512, L=32, H=32, D=128]; per (l,h): Linear(128->128) -> GELU -> Linear(128->128)
// R18 = R9 champion + dedicated H region (no x-overlay) -> 2 barriers/tile
// (was 3), neither draining vmcnt(0): barTop = vmcnt(32) (stores fly), barH =
// lgkm-only. Fingerprint preserved: {256 thr, 4 waves, BT=64, grid 1024,
// 2 blocks/CU} (LDS 80 KB, 160/80 = 2) -- the only config that keeps the
// L3 traffic credit (FETCH 197 MB; R10/R13/R16 all blew it).
#define LH      1024
#define Dd      128
#define BT      64            // batch rows per tile -> 32 KB f32 per x buffer
#define NTILE   8             // 512 / 64
#define XSTRIDE (LH * Dd)

typedef __attribute__((ext_vector_type(8))) short bf16x8;
typedef __attribute__((ext_vector_type(4))) float f32x4;
typedef const __attribute__((address_space(1))) uint32_t gu32;
typedef __attribute__((address_space(3))) uint32_t lu32;

static __device__ __forceinline__ short f2bf(float f) {
  return __builtin_bit_cast(short, (__bf16)f);
}

// tanh-form GELU as one sigmoid; |diff| vs erf-gelu ~3e-3 << 0.185 threshold
static __device__ __forceinline__ float gelu_fast(float v) {
  float v2 = v * v;
  float u2 = v * (1.5957691216f + 0.0713548163f * v2);
  return v / (1.0f + __expf(-u2));
}

// Top-of-tile barrier: vmcnt(32) + in-order retire (m135) proves DMA(t)
// (issued before this tile's 32 stores) is complete while the stores stay
// in flight. lgkmcnt(0) orders LDS. sched_barrier fences per rule #18.
#define BAR_TOP() do {                                           \
  __builtin_amdgcn_sched_barrier(0);                             \
  asm volatile("s_waitcnt vmcnt(32) lgkmcnt(0)" ::: "memory");   \
  __builtin_amdgcn_s_barrier();                                  \
  __builtin_amdgcn_sched_barrier(0);                             \
} while (0)

// H-visibility barrier: LDS-only drain; global loads/stores keep flying.
#define BAR_H() do {                                             \
  __builtin_amdgcn_sched_barrier(0);                             \
  asm volatile("s_waitcnt lgkmcnt(0)" ::: "memory");             \
  __builtin_amdgcn_s_barrier();                                  \
  __builtin_amdgcn_sched_barrier(0);                             \
} while (0)

__global__ __launch_bounds__(256, 2) void fused_mlp_persist(
    const float* __restrict__ x, const float* __restrict__ W1,
    const float* __restrict__ b1, const float* __restrict__ W2,
    const float* __restrict__ b2, float* __restrict__ out) {
  // x ping-pong: f32 [64 rows][32 chunks of 16B], chunk-index XOR-swizzled on
  // the GLOBAL source addr (global_load_lds writes LDS linearly, m104/m173).
  __shared__ alignas(16) char xbuf[2][BT * Dd * 4];   // 64 KB
  // H: dedicated bf16 [64][128], XOR-swizzled rows. Single buffer is safe:
  // H(t+1) writes occur after BAR_TOP(t+1), which each wave reaches only
  // after its GEMM2(t) H-reads (program order).
  __shared__ alignas(16) char Hbuf[BT * Dd * 2];      // 16 KB -> total 80 KB

  const int tid  = threadIdx.x;
  const int lane = tid & 63;
  const int wid  = tid >> 6;     // 4 waves, each owns 32 N-columns
  const int lr   = lane & 15;
  const int lg   = lane >> 4;

  const int lh = blockIdx.x;     // W reuse is intra-block
  const int n0 = wid * 32;

  const float* w1  = W1 + (size_t)lh * (Dd * Dd);
  const float* w2  = W2 + (size_t)lh * (Dd * Dd);
  const float* xlh = x   + (size_t)lh * Dd;
  float*       olh = out + (size_t)lh * Dd;

  // stage tile t into x buffer buf: 8 DMA issues/wave, 32 KB in flight
  auto stage = [&](int t, int buf) {
#pragma unroll
    for (int i = 0; i < 8; ++i) {
      const int slot = wid * 8 + i;          // wave-uniform 1KB LDS slot
      const int row  = slot * 2 + (lane >> 5);
      const int cp   = lane & 31;            // chunk position in LDS
      const int c    = cp ^ (row & 15);      // global chunk (bijective swz)
      const float* g = xlh + (size_t)(t * BT + row) * XSTRIDE + c * 4;
      __builtin_amdgcn_global_load_lds((gu32*)g,
                                       (lu32*)(xbuf[buf] + slot * 1024),
                                       16, 0, 0);
    }
  };

  // ---- prologue: DMA tile 0; gather ALL W fragments to regs (hidden under
  // the DMA flight); biases; one full-drain barrier.
  stage(0, 0);

  bf16x8 bw1[4][2], bw2[4][2];
#pragma unroll
  for (int ks = 0; ks < 4; ++ks)
#pragma unroll
    for (int nt = 0; nt < 2; ++nt) {
      const float* p1 = w1 + (size_t)(ks * 32 + lg * 8) * Dd + n0 + nt * 16 + lr;
      const float* p2 = w2 + (size_t)(ks * 32 + lg * 8) * Dd + n0 + nt * 16 + lr;
      bf16x8 a, b;
#pragma unroll
      for (int j = 0; j < 8; ++j) { a[j] = f2bf(p1[j * Dd]); b[j] = f2bf(p2[j * Dd]); }
      bw1[ks][nt] = a;
      bw2[ks][nt] = b;
    }

  const float bb1_0 = b1[lh * Dd + n0 + lr];
  const float bb1_1 = b1[lh * Dd + n0 + 16 + lr];
  const float bb2_0 = b2[lh * Dd + n0 + lr];
  const float bb2_1 = b2[lh * Dd + n0 + 16 + lr];

  __builtin_amdgcn_sched_barrier(0);
  asm volatile("s_waitcnt vmcnt(0) lgkmcnt(0)" ::: "memory");
  __builtin_amdgcn_s_barrier();
  __builtin_amdgcn_sched_barrier(0);

  for (int t = 0; t < NTILE; ++t) {
    const int cur = t & 1;

    // barTop (t>0): proves DMA(t) landed in xbuf[cur]; this tile's stores
    // predecessors (stores(t-1), 32 newest) stay in flight.
    if (t > 0) BAR_TOP();

    // DMA(t+1) -> xbuf[cur^1]: that buffer's last readers (GEMM1(t-1))
    // are all past barTop(t)/BAR_H(t-1). 1-tile flight time.
    if (t + 1 < NTILE) stage(t + 1, cur ^ 1);

    // ---------------- GEMM1: H = gelu(X @ W1 + b1) ----------------
    f32x4 acc[4][2];
#pragma unroll
    for (int mt = 0; mt < 4; ++mt) {
      acc[mt][0] = (f32x4){bb1_0, bb1_0, bb1_0, bb1_0};
      acc[mt][1] = (f32x4){bb1_1, bb1_1, bb1_1, bb1_1};
    }
#pragma unroll
    for (int ks = 0; ks < 4; ++ks) {
      bf16x8 af[4];
#pragma unroll
      for (int mt = 0; mt < 4; ++mt) {
        const int row = mt * 16 + lr;
        const int c0  = ks * 8 + lg * 2;
        const int m   = row & 15;
        const float4 lo = *(const float4*)(xbuf[cur] + row * 512 + ((c0)     ^ m) * 16);
        const float4 hi = *(const float4*)(xbuf[cur] + row * 512 + ((c0 + 1) ^ m) * 16);
        bf16x8 a;
        a[0] = f2bf(lo.x); a[1] = f2bf(lo.y); a[2] = f2bf(lo.z); a[3] = f2bf(lo.w);
        a[4] = f2bf(hi.x); a[5] = f2bf(hi.y); a[6] = f2bf(hi.z); a[7] = f2bf(hi.w);
        af[mt] = a;
      }
#pragma unroll
      for (int mt = 0; mt < 4; ++mt)
#pragma unroll
        for (int nt = 0; nt < 2; ++nt)
          acc[mt][nt] = __builtin_amdgcn_mfma_f32_16x16x32_bf16(af[mt], bw1[ks][nt], acc[mt][nt], 0, 0, 0);
    }

    // GELU in regs, write H to the dedicated region (no overlay hazard ->
    // no pre-write barrier needed)
#pragma unroll
    for (int mt = 0; mt < 4; ++mt)
#pragma unroll
      for (int nt = 0; nt < 2; ++nt) {
        const int e = n0 + nt * 16 + lr;
#pragma unroll
        for (int r = 0; r < 4; ++r) {
          const int b = mt * 16 + lg * 4 + r;   // C/D row = (lane>>4)*4 + reg
          const int off = (b * 256 + e * 2) ^ ((b & 7) << 4);
          *(short*)(Hbuf + off) = f2bf(gelu_fast(acc[mt][nt][r]));
        }
      }

    BAR_H();   // H visible; DMA/stores keep flying

    // ---------------- GEMM2: out = H @ W2 + b2 (W2 in regs) ----------
    f32x4 acc2[4][2];
#pragma unroll
    for (int mt = 0; mt < 4; ++mt) {
      acc2[mt][0] = (f32x4){bb2_0, bb2_0, bb2_0, bb2_0};
      acc2[mt][1] = (f32x4){bb2_1, bb2_1, bb2_1, bb2_1};
    }
#pragma unroll
    for (int ks = 0; ks < 4; ++ks) {
      const int k2 = (ks * 32 + lg * 8) * 2;   // byte offset of 16B H granule
#pragma unroll
      for (int mt = 0; mt < 4; ++mt) {
        const int b = mt * 16 + lr;
        const int off = (b * 256 + k2) ^ ((b & 7) << 4);
        bf16x8 a = *(const bf16x8*)(Hbuf + off);
#pragma unroll
        for (int nt = 0; nt < 2; ++nt)
          acc2[mt][nt] = __builtin_amdgcn_mfma_f32_16x16x32_bf16(a, bw2[ks][nt], acc2[mt][nt], 0, 0, 0);
      }
    }

    // epilogue: 32 f32 stores (64B contiguous per 16-lane group); they drain
    // under the next tile's GEMM1 (barTop only waits vmcnt(32)).
    {
      float* ob = olh + (size_t)(t * BT) * XSTRIDE;
#pragma unroll
      for (int mt = 0; mt < 4; ++mt)
#pragma unroll
        for (int nt = 0; nt < 2; ++nt) {
          const int e = n0 + nt * 16 + lr;
#pragma unroll
          for (int r = 0; r < 4; ++r) {
            const int b = mt * 16 + lg * 4 + r;
            ob[(size_t)b * XSTRIDE + e] = acc2[mt][nt][r];
          }
        }
    }
  }
}

extern "C" void kernel_launch(void* const* d_in, const int* in_sizes, int n_in,
                              void* d_out, int out_size, void* d_ws, size_t ws_size,
                              hipStream_t stream) {
  (void)in_sizes; (void)n_in; (void)d_ws; (void)ws_size; (void)out_size;
  const float* x  = (const float*)d_in[0];
  const float* W1 = (const float*)d_in[1];
  const float* b1 = (const float*)d_in[2];
  const float* W2 = (const float*)d_in[3];
  const float* b2 = (const float*)d_in[4];
  float* out = (float*)d_out;
  fused_mlp_persist<<<dim3(LH), dim3(256), 0, stream>>>(x, W1, b1, W2, b2, out);
}